// Round 1
// baseline (417.989 us; speedup 1.0000x reference)
//
#include <hip/hip_runtime.h>
#include <cstdint>

typedef __bf16 bf16;
typedef __bf16 bf16x8 __attribute__((ext_vector_type(8)));
typedef __bf16 bf16x4 __attribute__((ext_vector_type(4)));
typedef float f32x4 __attribute__((ext_vector_type(4)));

#define DIMN 2048
#define SEQ  2048
#define NH   16
#define HD   128

// -------- async global->LDS 16B helper (m97 pattern) --------
__device__ __forceinline__ void gld_lds16(const bf16* g, bf16* l) {
    __builtin_amdgcn_global_load_lds(
        (const __attribute__((address_space(1))) void*)g,
        (__attribute__((address_space(3))) void*)l,
        16, 0, 0);
}

// -------- all fp32->bf16 casts in ONE launch --------
__global__ __launch_bounds__(256) void cast_all(
    const float* __restrict__ x,
    const float* __restrict__ wq, const float* __restrict__ wk,
    const float* __restrict__ wv, const float* __restrict__ wo,
    bf16* __restrict__ xb,
    bf16* __restrict__ wqb, bf16* __restrict__ wkb,
    bf16* __restrict__ wvb, bf16* __restrict__ wob)
{
    int id = blockIdx.x;
    const float* src; bf16* dst; int i;
    if (id < 8192) { src = x; dst = xb; i = id * 256 + threadIdx.x; }
    else {
        id -= 8192;
        int w = id >> 12; id &= 4095;
        src = (w == 0) ? wq : (w == 1) ? wk : (w == 2) ? wv : wo;
        dst = (w == 0) ? wqb : (w == 1) ? wkb : (w == 2) ? wvb : wob;
        i = id * 256 + threadIdx.x;
    }
    float4 v = ((const float4*)src)[i];
    bf16x4 o;
    o[0] = (bf16)v.x; o[1] = (bf16)v.y; o[2] = (bf16)v.z; o[3] = (bf16)v.w;
    ((bf16x4*)dst)[i] = o;
}

// -------- 128x128 m97-structure GEMM: kept for the output projection only
// (512 blocks -> 2 blocks/CU, full machine; 256^2 would leave half the chip idle)
template<int OUT_F32>
__global__ __launch_bounds__(256) void gemm_bt(
    const bf16* __restrict__ A,
    const bf16* __restrict__ Bw0, const bf16* __restrict__ Bw1, const bf16* __restrict__ Bw2,
    const float* __restrict__ bias0, const float* __restrict__ bias1, const float* __restrict__ bias2,
    void* __restrict__ C0, void* __restrict__ C1, void* __restrict__ C2)
{
    const int K = DIMN, N = DIMN;
    const bf16* Bw = Bw0; const float* bias = bias0; void* Cout = C0;
    if (blockIdx.z == 1) { Bw = Bw1; bias = bias1; Cout = C1; }
    if (blockIdx.z == 2) { Bw = Bw2; bias = bias2; Cout = C2; }

    __shared__ __attribute__((aligned(16))) bf16 As[128 * 64];
    __shared__ __attribute__((aligned(16))) bf16 Bs[128 * 64];

    const int t    = threadIdx.x;
    const int lane = t & 63, wave = t >> 6;
    const int l15  = lane & 15, quad = lane >> 4;
    const int wm   = (wave >> 1) * 64, wn = (wave & 1) * 64;
    const long bm  = (long)blockIdx.y * 128;
    const long bn  = (long)blockIdx.x * 128;

    const bf16* agp[4]; const bf16* bgp[4]; bf16* asd[4]; bf16* bsd[4];
#pragma unroll
    for (int it = 0; it < 4; it++) {
        int fs  = it * 256 + t;
        int row = fs >> 3;
        int gs  = (fs & 7) ^ (row & 7);
        agp[it] = A  + (bm + row) * (long)K + gs * 8;
        bgp[it] = Bw + (bn + row) * (long)K + gs * 8;
        asd[it] = As + fs * 8;
        bsd[it] = Bs + fs * 8;
    }
    const int swl = l15 & 7;

    f32x4 acc[4][4] = {};

    for (int k0 = 0; k0 < K; k0 += 64) {
#pragma unroll
        for (int it = 0; it < 4; it++) {
            gld_lds16(agp[it] + k0, asd[it]);
            gld_lds16(bgp[it] + k0, bsd[it]);
        }
        __syncthreads();

#pragma unroll
        for (int ks2 = 0; ks2 < 2; ks2++) {
            const int sw = ((ks2 * 4 + quad) ^ swl) * 8;
            bf16x8 af[4], bfr[4];
#pragma unroll
            for (int i = 0; i < 4; i++)
                af[i] = *(const bf16x8*)(As + (wm + i * 16 + l15) * 64 + sw);
#pragma unroll
            for (int j = 0; j < 4; j++)
                bfr[j] = *(const bf16x8*)(Bs + (wn + j * 16 + l15) * 64 + sw);
#pragma unroll
            for (int i = 0; i < 4; i++)
#pragma unroll
                for (int j = 0; j < 4; j++)
                    acc[i][j] = __builtin_amdgcn_mfma_f32_16x16x32_bf16(af[i], bfr[j], acc[i][j], 0, 0, 0);
        }
        __syncthreads();
    }

#pragma unroll
    for (int j = 0; j < 4; j++) {
        const long col = bn + wn + j * 16 + l15;
        const float bv = bias[col];
#pragma unroll
        for (int i = 0; i < 4; i++) {
            const long row0 = bm + wm + i * 16 + quad * 4;
#pragma unroll
            for (int r = 0; r < 4; r++) {
                float v = acc[i][j][r] + bv;
                if (OUT_F32) ((float*)Cout)[(row0 + r) * N + col] = v;
                else         ((bf16*)Cout)[(row0 + r) * N + col] = (bf16)v;
            }
        }
    }
}

// ======== NEW: 256x256 8-phase GEMM (T2+T3+T4+T5) for the QKV projections ========
// 512 threads = 8 waves (2M x 4N), per-wave C = 128x64, BK=64, LDS 128 KiB (2 dbuf).
// Stage units: A-quarters Aq0..3 (64 rows: 32 from each 128-row half; read by exactly
// one phase of the tile) and B-quarters B0..3 (64 rows; LDS-read ONLY at the tile's
// phase-1 into bfrag registers, reused across phases 2-4).
// Per phase: {ds-reads ; 2 stage units} -> barrier -> MFMA(setprio) -> barrier.
// vmcnt(3) ONLY at phases 4 and 8 (never 0): the oldest still-needed unit is always
// 4th-from-last in issue order (verified against the stage table below).
//
//   ph1: stage O.B0,B1      ph5: stage E'.B0,B1
//   ph2: stage O.B2,B3      ph6: stage E'.B2,B3
//   ph3: stage O.Aq3,E'.Aq0 ph7: stage E'.Aq3,O'.Aq0
//   ph4: stage E'.Aq1,Aq2 +vmcnt(3)   ph8: stage O'.Aq1,Aq2 +vmcnt(3)
//
// Race-freedom: every staged region's previous reader finished >=1 end-barrier before
// the stage issue, and intra-phase stage targets are disjoint from that phase's reads.
#define VMCNT3 asm volatile("s_waitcnt vmcnt(3)" ::: "memory")

#define STAGE_AQ(bsel, kt, q) do {                                          \
    const int row_ = (q) * 32 + arow_base;                                  \
    gld_lds16(Ag + (long)row_ * DIMN + (kt) * 64 + ((ssg ^ (row_ & 7)) << 3), \
              &As[bsel][(row_ * 8 + ssg) * 8]);                             \
} while (0)

#define STAGE_BU(bsel, kt, u) do {                                          \
    const int row_ = (u) * 64 + srl;                                        \
    gld_lds16(Bg + (long)row_ * DIMN + (kt) * 64 + ((ssg ^ (row_ & 7)) << 3), \
              &Bs[bsel][(row_ * 8 + ssg) * 8]);                             \
} while (0)

#define PHASE(bsel, p0, STAGES, ...) do {                                   \
    bf16x8 af_[2][2];                                                       \
    _Pragma("unroll")                                                       \
    for (int im = 0; im < 2; ++im) {                                        \
        const int ar = wm * 128 + ((p0) * 2 + im) * 16 + l15;               \
        _Pragma("unroll")                                                   \
        for (int ks = 0; ks < 2; ++ks)                                      \
            af_[im][ks] = *(const bf16x8*)(&As[bsel][(ar * 8 + ((ks * 4 + quad) ^ swl)) * 8]); \
    }                                                                       \
    if ((p0) == 0) {                                                        \
        _Pragma("unroll")                                                   \
        for (int j = 0; j < 4; ++j) {                                       \
            const int br = wn * 64 + j * 16 + l15;                          \
            _Pragma("unroll")                                               \
            for (int ks = 0; ks < 2; ++ks)                                  \
                bfrag[j][ks] = *(const bf16x8*)(&Bs[bsel][(br * 8 + ((ks * 4 + quad) ^ swl)) * 8]); \
        }                                                                   \
    }                                                                       \
    STAGES;                                                                 \
    asm volatile("" ::: "memory");                                          \
    __builtin_amdgcn_s_barrier();                                           \
    asm volatile("" ::: "memory");                                          \
    __builtin_amdgcn_s_setprio(1);                                          \
    _Pragma("unroll")                                                       \
    for (int im = 0; im < 2; ++im)                                          \
        _Pragma("unroll")                                                   \
        for (int j = 0; j < 4; ++j)                                         \
            _Pragma("unroll")                                               \
            for (int ks = 0; ks < 2; ++ks)                                  \
                acc[(p0) * 2 + im][j] = __builtin_amdgcn_mfma_f32_16x16x32_bf16( \
                    af_[im][ks], bfrag[j][ks], acc[(p0) * 2 + im][j], 0, 0, 0); \
    __builtin_amdgcn_s_setprio(0);                                          \
    __VA_ARGS__;                                                            \
    asm volatile("" ::: "memory");                                          \
    __builtin_amdgcn_s_barrier();                                           \
    asm volatile("" ::: "memory");                                          \
} while (0)

__global__ __launch_bounds__(512, 2) void gemm256(
    const bf16* __restrict__ A,
    const bf16* __restrict__ Bw0, const bf16* __restrict__ Bw1, const bf16* __restrict__ Bw2,
    const float* __restrict__ bias0, const float* __restrict__ bias1, const float* __restrict__ bias2,
    bf16* __restrict__ C0, bf16* __restrict__ C1, bf16* __restrict__ C2)
{
    const int N = DIMN;
    const bf16* Bw = Bw0; const float* bias = bias0; bf16* Cout = C0;
    if (blockIdx.z == 1) { Bw = Bw1; bias = bias1; Cout = C1; }
    if (blockIdx.z == 2) { Bw = Bw2; bias = bias2; Cout = C2; }

    __shared__ __attribute__((aligned(16))) bf16 As[2][256 * 64];
    __shared__ __attribute__((aligned(16))) bf16 Bs[2][256 * 64];

    const int t    = threadIdx.x;
    const int lane = t & 63, wave = t >> 6;
    const int l15  = lane & 15, quad = lane >> 4;
    const int wm   = wave >> 2, wn = wave & 3;        // 2 x 4 wave grid
    const int swl  = l15 & 7;

    // bijective XCD swizzle over the 128-wg (x,y) grid: each XCD owns 2 row-panels
    const int id  = blockIdx.y * 8 + blockIdx.x;
    const int wg  = (id & 7) * 16 + (id >> 3);
    const long bm = (long)(wg >> 3) * 256;
    const long bn = (long)(wg & 7) * 256;

    const bf16* Ag = A  + bm * DIMN;
    const bf16* Bg = Bw + bn * DIMN;

    // staging geometry: 512 threads x 16B = one 8KB unit (64 rows x 8 segs)
    const int srl = t >> 3, ssg = t & 7;
    const int arow_base = (srl & 31) + ((srl >> 5) << 7);   // 32 rows of each half

    f32x4  acc[8][4] = {};
    bf16x8 bfrag[4][2];

    // prologue: tile0 complete + tile1.Aq0-2 ; vmcnt(3) -> tile0 fully landed
    STAGE_BU(0, 0, 0); STAGE_BU(0, 0, 1); STAGE_BU(0, 0, 2); STAGE_BU(0, 0, 3);
    STAGE_AQ(0, 0, 0); STAGE_AQ(0, 0, 1); STAGE_AQ(0, 0, 2); STAGE_AQ(0, 0, 3);
    STAGE_AQ(1, 1, 0); STAGE_AQ(1, 1, 1); STAGE_AQ(1, 1, 2);
    VMCNT3;
    asm volatile("" ::: "memory");
    __builtin_amdgcn_s_barrier();
    asm volatile("" ::: "memory");

    for (int it = 0; it < 16; ++it) {
        const int tO  = 2 * it + 1;
        const int tE2 = (2 * it + 2) & 31;   // wrap on tail: staged-but-never-read
        const int tO2 = (2 * it + 3) & 31;
        // ---- even tile (buf0), phases 1-4 ----
        PHASE(0, 0, { STAGE_BU(1, tO, 0); STAGE_BU(1, tO, 1); });
        PHASE(0, 1, { STAGE_BU(1, tO, 2); STAGE_BU(1, tO, 3); });
        PHASE(0, 2, { STAGE_AQ(1, tO, 3); STAGE_AQ(0, tE2, 0); });
        PHASE(0, 3, { STAGE_AQ(0, tE2, 1); STAGE_AQ(0, tE2, 2); }, VMCNT3);
        // ---- odd tile (buf1), phases 5-8 ----
        PHASE(1, 0, { STAGE_BU(0, tE2, 0); STAGE_BU(0, tE2, 1); });
        PHASE(1, 1, { STAGE_BU(0, tE2, 2); STAGE_BU(0, tE2, 3); });
        PHASE(1, 2, { STAGE_AQ(0, tE2, 3); STAGE_AQ(1, tO2, 0); });
        PHASE(1, 3, { STAGE_AQ(1, tO2, 1); STAGE_AQ(1, tO2, 2); }, VMCNT3);
    }

#pragma unroll
    for (int j = 0; j < 4; ++j) {
        const long col = bn + wn * 64 + j * 16 + l15;
        const float bv = bias[col];
#pragma unroll
        for (int i = 0; i < 8; ++i) {
            const long row0 = bm + wm * 128 + i * 16 + quad * 4;
#pragma unroll
            for (int r = 0; r < 4; ++r)
                Cout[(row0 + r) * N + col] = (bf16)(acc[i][j][r] + bv);
        }
    }
}

// -------- fused (RMSNorm+RoPE on q,k) + (V transpose) in one launch --------
__global__ __launch_bounds__(256) void norm_prep(
    bf16* __restrict__ q, bf16* __restrict__ k,
    const float* __restrict__ gq, const float* __restrict__ gk,
    const float* __restrict__ freqs,
    const bf16* __restrict__ vin, bf16* __restrict__ vt)
{
    const int id = blockIdx.x;
    const int t = threadIdx.x;
    if (id < 8192) {
        const int qk  = id >> 12;
        const int row = id & 4095;                 // b*SEQ + s
        bf16* ptr = qk ? k : q;
        const float* g = qk ? gk : gq;
        const float osc = qk ? 1.0f : 0.08838834764831845f;   // fold 1/sqrt(HD) into Q
        const int s = row & (SEQ - 1);
        const int lane = t & 63, wave = t >> 6;

        bf16* base = ptr + (long)row * DIMN + t * 8;
        bf16x8 raw = *(const bf16x8*)base;
        float v[8]; float ss = 0.f;
#pragma unroll
        for (int j = 0; j < 8; j++) { v[j] = (float)raw[j]; ss += v[j] * v[j]; }
#pragma unroll
        for (int off = 32; off; off >>= 1) ss += __shfl_xor(ss, off, 64);
        __shared__ float red[4];
        if (lane == 0) red[wave] = ss;
        __syncthreads();
        float tot = red[0] + red[1] + red[2] + red[3];
        float rn = rsqrtf(tot * (1.0f / DIMN) + 1e-6f);

        const int e0 = t * 8;
        bf16x8 o;
#pragma unroll
        for (int pp = 0; pp < 4; pp++) {
            int e = e0 + pp * 2;
            float xr = v[pp * 2]     * rn * g[e];
            float xi = v[pp * 2 + 1] * rn * g[e + 1];
            int lc = (e >> 1) & 63;
            float cr = freqs[s * 128 + lc * 2];
            float ci = freqs[s * 128 + lc * 2 + 1];
            o[pp * 2]     = (bf16)((xr * cr - xi * ci) * osc);
            o[pp * 2 + 1] = (bf16)((xr * ci + xi * cr) * osc);
        }
        *(bf16x8*)base = o;
    } else {
        const int tid = id - 8192;
        const int b = tid >> 10, rem = tid & 1023;
        const int st = rem & 31, ct = rem >> 5;
        __shared__ float tile[64][65];
        const int tx = t & 63, ty = t >> 6;
#pragma unroll
        for (int ii = 0; ii < 16; ii++) {
            int r = ii * 4 + ty;
            tile[r][tx] = (float)vin[((long)(b * SEQ + st * 64 + r)) * DIMN + ct * 64 + tx];
        }
        __syncthreads();
#pragma unroll
        for (int ii = 0; ii < 16; ii++) {
            int c = ii * 4 + ty;
            vt[((long)(b * DIMN + ct * 64 + c)) * SEQ + st * 64 + tx] = (bf16)tile[tx][c];
        }
    }
}

// -------- flash-style attention v3 (unchanged this round) --------
__global__ __launch_bounds__(512, 2) void attention(
    const bf16* __restrict__ Q, const bf16* __restrict__ Kb,
    const bf16* __restrict__ Vt, bf16* __restrict__ O)
{
    __shared__ __attribute__((aligned(16))) bf16 Ksh[2][64 * 128];   // [kr][d], seg^=(kr&15)
    __shared__ __attribute__((aligned(16))) bf16 Vsh[2][128 * 64];   // [d][kr], seg^=(d&7)
    __shared__ __attribute__((aligned(16))) bf16 Psh[8][32 * 72];    // per-wave P[m][kr]
    __shared__ float Lsh[8][32];

    const int t = threadIdx.x;
    const int lane = t & 63, w = t >> 6;
    const int l15 = lane & 15, quad = lane >> 4;
    const int bh = blockIdx.x, b = bh >> 4, h = bh & 15;   // x = head: XCD-local K/V
    const int qt = blockIdx.y;
    const long qrow0 = (long)b * SEQ + qt * 256 + w * 32;
    const bf16* qbase = Q  + qrow0 * DIMN + h * HD;
    const bf16* kbase = Kb + (long)b * SEQ * DIMN + h * HD;
    const bf16* vbase = Vt + (long)bh * HD * SEQ;

    bf16x8 qf[2][4];
#pragma unroll
    for (int im = 0; im < 2; im++)
#pragma unroll
        for (int kd = 0; kd < 4; kd++)
            qf[im][kd] = *(const bf16x8*)(qbase + (long)(im * 16 + l15) * DIMN + kd * 32 + quad * 8);

    long koff[2], voff[2];
#pragma unroll
    for (int it = 0; it < 2; it++) {
        int fs = it * 512 + t;
        int kr = fs >> 4, kp = fs & 15;
        koff[it] = (long)kr * DIMN + (kp ^ (kr & 15)) * 8;
        int dr = fs >> 3, vp = fs & 7;
        voff[it] = (long)dr * SEQ + (vp ^ (dr & 7)) * 8;
    }

    f32x4 o_acc[2][8] = {};
    float Lt[2] = {0.f, 0.f};

#pragma unroll
    for (int it = 0; it < 2; it++) {
        gld_lds16(kbase + koff[it], &Ksh[0][(it * 512 + t) * 8]);
        gld_lds16(vbase + voff[it], &Vsh[0][(it * 512 + t) * 8]);
    }
    __syncthreads();

    for (int kt = 0; kt < 32; kt++) {
        const int cur = kt & 1;
        if (kt < 31) {
            const bf16* kg = kbase + (long)((kt + 1) * 64) * DIMN;
            const bf16* vg = vbase + (kt + 1) * 64;
#pragma unroll
            for (int it = 0; it < 2; it++) {
                gld_lds16(kg + koff[it], &Ksh[cur ^ 1][(it * 512 + t) * 8]);
                gld_lds16(vg + voff[it], &Vsh[cur ^ 1][(it * 512 + t) * 8]);
            }
        }
        const bf16* K0 = Ksh[cur];
        const bf16* V0 = Vsh[cur];

        f32x4 st[4][2] = {};
#pragma unroll
        for (int jk = 0; jk < 4; jk++)
#pragma unroll
            for (int kd = 0; kd < 4; kd++) {
                bf16x8 kf = *(const bf16x8*)(K0 + (jk * 16 + l15) * 128 + (((kd * 4 + quad) ^ l15) & 15) * 8);
                st[jk][0] = __builtin_amdgcn_mfma_f32_16x16x32_bf16(kf, qf[0][kd], st[jk][0], 0, 0, 0);
                st[jk][1] = __builtin_amdgcn_mfma_f32_16x16x32_bf16(kf, qf[1][kd], st[jk][1], 0, 0, 0);
            }

#pragma unroll
        for (int im = 0; im < 2; im++) {
            float part = 0.f;
#pragma unroll
            for (int jk = 0; jk < 4; jk++) {
                bf16x4 pk;
#pragma unroll
                for (int r = 0; r < 4; r++) {
                    float e = __expf(st[jk][im][r]);
                    part += e;
                    pk[r] = (bf16)e;
                }
                *(bf16x4*)(Psh[w] + (im * 16 + l15) * 72 + jk * 16 + quad * 4) = pk;
            }
            Lt[im] += part;
        }

#pragma unroll
        for (int kd2 = 0; kd2 < 2; kd2++) {
            bf16x8 pa[2];
            pa[0] = *(const bf16x8*)(Psh[w] + (l15)      * 72 + kd2 * 32 + quad * 8);
            pa[1] = *(const bf16x8*)(Psh[w] + (16 + l15) * 72 + kd2 * 32 + quad * 8);
#pragma unroll
            for (int dj = 0; dj < 8; dj++) {
                bf16x8 vfr = *(const bf16x8*)(V0 + (dj * 16 + l15) * 64 + (((kd2 * 4 + quad) ^ l15) & 7) * 8);
                o_acc[0][dj] = __builtin_amdgcn_mfma_f32_16x16x32_bf16(pa[0], vfr, o_acc[0][dj], 0, 0, 0);
                o_acc[1][dj] = __builtin_amdgcn_mfma_f32_16x16x32_bf16(pa[1], vfr, o_acc[1][dj], 0, 0, 0);
            }
        }
        __syncthreads();
    }

#pragma unroll
    for (int im = 0; im < 2; im++) {
        Lt[im] += __shfl_xor(Lt[im], 16, 64);
        Lt[im] += __shfl_xor(Lt[im], 32, 64);
    }
    if (quad == 0) { Lsh[w][l15] = Lt[0]; Lsh[w][16 + l15] = Lt[1]; }
    __syncthreads();

#pragma unroll
    for (int im = 0; im < 2; im++)
#pragma unroll
        for (int r = 0; r < 4; r++) {
            float inv = 1.0f / Lsh[w][im * 16 + quad * 4 + r];
            long orow = qrow0 + im * 16 + quad * 4 + r;
#pragma unroll
            for (int dj = 0; dj < 8; dj++)
                O[orow * DIMN + h * HD + dj * 16 + l15] = (bf16)(o_acc[im][dj][r] * inv);
        }
}

extern "C" void kernel_launch(void* const* d_in, const int* in_sizes, int n_in,
                              void* d_out, int out_size, void* d_ws, size_t ws_size,
                              hipStream_t stream) {
    const float* x     = (const float*)d_in[0];
    const float* freqs = (const float*)d_in[1];
    const float* wq    = (const float*)d_in[2];
    const float* bq    = (const float*)d_in[3];
    const float* wk    = (const float*)d_in[4];
    const float* bk    = (const float*)d_in[5];
    const float* wv    = (const float*)d_in[6];
    const float* bv    = (const float*)d_in[7];
    const float* wo    = (const float*)d_in[8];
    const float* bo    = (const float*)d_in[9];
    const float* gq    = (const float*)d_in[10];
    const float* gk    = (const float*)d_in[11];
    float* out = (float*)d_out;

    const size_t MAT  = (size_t)4096 * 2048 * 2;   // 16 MiB
    const size_t WMAT = (size_t)2048 * 2048 * 2;   // 8 MiB
    char* p = (char*)d_ws;
    bf16* xb  = (bf16*)p; p += MAT;
    bf16* wqb = (bf16*)p; p += WMAT;
    bf16* wkb = (bf16*)p; p += WMAT;
    bf16* wvb = (bf16*)p; p += WMAT;
    bf16* wob = (bf16*)p; p += WMAT;
    bf16* qb  = (bf16*)p; p += MAT;
    bf16* kb  = (bf16*)p; p += MAT;
    bf16* vb  = (bf16*)p; p += MAT;
    bf16* vt  = (bf16*)p; p += MAT;
    bf16* attn = qb;   // alias (safe: per-block exclusive row/col regions)

    cast_all<<<24576, 256, 0, stream>>>(x, wq, wk, wv, wo, xb, wqb, wkb, wvb, wob);

    gemm256<<<dim3(8, 16, 3), 512, 0, stream>>>(xb, wqb, wkb, wvb,
                                                bq, bk, bv, qb, kb, vb);
    norm_prep<<<10240, 256, 0, stream>>>(qb, kb, gq, gk, freqs, vb, vt);
    attention<<<dim3(32, 8), 512, 0, stream>>>(qb, kb, vt, attn);
    gemm_bt<1><<<dim3(16, 32, 1), 256, 0, stream>>>(attn, wob, wob, wob,
                                                    bo, bo, bo, out, out, out);
}

// Round 2
// 399.828 us; speedup vs baseline: 1.0454x; 1.0454x over previous
//
#include <hip/hip_runtime.h>
#include <cstdint>

typedef __bf16 bf16;
typedef __bf16 bf16x8 __attribute__((ext_vector_type(8)));
typedef __bf16 bf16x4 __attribute__((ext_vector_type(4)));
typedef float f32x4 __attribute__((ext_vector_type(4)));

#define DIMN 2048
#define SEQ  2048
#define NH   16
#define HD   128

// -------- async global->LDS 16B helper (m97 pattern) --------
__device__ __forceinline__ void gld_lds16(const bf16* g, bf16* l) {
    __builtin_amdgcn_global_load_lds(
        (const __attribute__((address_space(1))) void*)g,
        (__attribute__((address_space(3))) void*)l,
        16, 0, 0);
}

// -------- all fp32->bf16 casts in ONE launch --------
__global__ __launch_bounds__(256) void cast_all(
    const float* __restrict__ x,
    const float* __restrict__ wq, const float* __restrict__ wk,
    const float* __restrict__ wv, const float* __restrict__ wo,
    bf16* __restrict__ xb,
    bf16* __restrict__ wqb, bf16* __restrict__ wkb,
    bf16* __restrict__ wvb, bf16* __restrict__ wob)
{
    int id = blockIdx.x;
    const float* src; bf16* dst; int i;
    if (id < 8192) { src = x; dst = xb; i = id * 256 + threadIdx.x; }
    else {
        id -= 8192;
        int w = id >> 12; id &= 4095;
        src = (w == 0) ? wq : (w == 1) ? wk : (w == 2) ? wv : wo;
        dst = (w == 0) ? wqb : (w == 1) ? wkb : (w == 2) ? wvb : wob;
        i = id * 256 + threadIdx.x;
    }
    float4 v = ((const float4*)src)[i];
    bf16x4 o;
    o[0] = (bf16)v.x; o[1] = (bf16)v.y; o[2] = (bf16)v.z; o[3] = (bf16)v.w;
    ((bf16x4*)dst)[i] = o;
}

// -------- 128x128 m97-structure GEMM (known-good 845 TF on this shape).
// QKV runs as THREE z=1 dispatches: 512 blocks each = exact 2-blocks/CU round,
// and ~41 us/dispatch keeps GEMM out of the top-5 so attention's counters surface.
template<int OUT_F32>
__global__ __launch_bounds__(256) void gemm_bt(
    const bf16* __restrict__ A,
    const bf16* __restrict__ Bw0, const bf16* __restrict__ Bw1, const bf16* __restrict__ Bw2,
    const float* __restrict__ bias0, const float* __restrict__ bias1, const float* __restrict__ bias2,
    void* __restrict__ C0, void* __restrict__ C1, void* __restrict__ C2)
{
    const int K = DIMN, N = DIMN;
    const bf16* Bw = Bw0; const float* bias = bias0; void* Cout = C0;
    if (blockIdx.z == 1) { Bw = Bw1; bias = bias1; Cout = C1; }
    if (blockIdx.z == 2) { Bw = Bw2; bias = bias2; Cout = C2; }

    __shared__ __attribute__((aligned(16))) bf16 As[128 * 64];
    __shared__ __attribute__((aligned(16))) bf16 Bs[128 * 64];

    const int t    = threadIdx.x;
    const int lane = t & 63, wave = t >> 6;
    const int l15  = lane & 15, quad = lane >> 4;
    const int wm   = (wave >> 1) * 64, wn = (wave & 1) * 64;
    const long bm  = (long)blockIdx.y * 128;
    const long bn  = (long)blockIdx.x * 128;

    const bf16* agp[4]; const bf16* bgp[4]; bf16* asd[4]; bf16* bsd[4];
#pragma unroll
    for (int it = 0; it < 4; it++) {
        int fs  = it * 256 + t;
        int row = fs >> 3;
        int gs  = (fs & 7) ^ (row & 7);
        agp[it] = A  + (bm + row) * (long)K + gs * 8;
        bgp[it] = Bw + (bn + row) * (long)K + gs * 8;
        asd[it] = As + fs * 8;
        bsd[it] = Bs + fs * 8;
    }
    const int swl = l15 & 7;

    f32x4 acc[4][4] = {};

    for (int k0 = 0; k0 < K; k0 += 64) {
#pragma unroll
        for (int it = 0; it < 4; it++) {
            gld_lds16(agp[it] + k0, asd[it]);
            gld_lds16(bgp[it] + k0, bsd[it]);
        }
        __syncthreads();

#pragma unroll
        for (int ks2 = 0; ks2 < 2; ks2++) {
            const int sw = ((ks2 * 4 + quad) ^ swl) * 8;
            bf16x8 af[4], bfr[4];
#pragma unroll
            for (int i = 0; i < 4; i++)
                af[i] = *(const bf16x8*)(As + (wm + i * 16 + l15) * 64 + sw);
#pragma unroll
            for (int j = 0; j < 4; j++)
                bfr[j] = *(const bf16x8*)(Bs + (wn + j * 16 + l15) * 64 + sw);
#pragma unroll
            for (int i = 0; i < 4; i++)
#pragma unroll
                for (int j = 0; j < 4; j++)
                    acc[i][j] = __builtin_amdgcn_mfma_f32_16x16x32_bf16(af[i], bfr[j], acc[i][j], 0, 0, 0);
        }
        __syncthreads();
    }

#pragma unroll
    for (int j = 0; j < 4; j++) {
        const long col = bn + wn + j * 16 + l15;
        const float bv = bias[col];
#pragma unroll
        for (int i = 0; i < 4; i++) {
            const long row0 = bm + wm + i * 16 + quad * 4;
#pragma unroll
            for (int r = 0; r < 4; r++) {
                float v = acc[i][j][r] + bv;
                if (OUT_F32) ((float*)Cout)[(row0 + r) * N + col] = v;
                else         ((bf16*)Cout)[(row0 + r) * N + col] = (bf16)v;
            }
        }
    }
}

// -------- fused (RMSNorm+RoPE on q,k) + (V transpose) in one launch --------
// Transpose global I/O vectorized to bf16x8 (16B/lane); LDS stays float[64][65]
// (stride 65 = 1 mod 32 -> column reads conflict-free).
__global__ __launch_bounds__(256) void norm_prep(
    bf16* __restrict__ q, bf16* __restrict__ k,
    const float* __restrict__ gq, const float* __restrict__ gk,
    const float* __restrict__ freqs,
    const bf16* __restrict__ vin, bf16* __restrict__ vt)
{
    const int id = blockIdx.x;
    const int t = threadIdx.x;
    if (id < 8192) {
        const int qk  = id >> 12;
        const int row = id & 4095;                 // b*SEQ + s
        bf16* ptr = qk ? k : q;
        const float* g = qk ? gk : gq;
        const float osc = qk ? 1.0f : 0.08838834764831845f;   // fold 1/sqrt(HD) into Q
        const int s = row & (SEQ - 1);
        const int lane = t & 63, wave = t >> 6;

        bf16* base = ptr + (long)row * DIMN + t * 8;
        bf16x8 raw = *(const bf16x8*)base;
        float v[8]; float ss = 0.f;
#pragma unroll
        for (int j = 0; j < 8; j++) { v[j] = (float)raw[j]; ss += v[j] * v[j]; }
#pragma unroll
        for (int off = 32; off; off >>= 1) ss += __shfl_xor(ss, off, 64);
        __shared__ float red[4];
        if (lane == 0) red[wave] = ss;
        __syncthreads();
        float tot = red[0] + red[1] + red[2] + red[3];
        float rn = rsqrtf(tot * (1.0f / DIMN) + 1e-6f);

        const int e0 = t * 8;
        bf16x8 o;
#pragma unroll
        for (int pp = 0; pp < 4; pp++) {
            int e = e0 + pp * 2;
            float xr = v[pp * 2]     * rn * g[e];
            float xi = v[pp * 2 + 1] * rn * g[e + 1];
            int lc = (e >> 1) & 63;
            float cr = freqs[s * 128 + lc * 2];
            float ci = freqs[s * 128 + lc * 2 + 1];
            o[pp * 2]     = (bf16)((xr * cr - xi * ci) * osc);
            o[pp * 2 + 1] = (bf16)((xr * ci + xi * cr) * osc);
        }
        *(bf16x8*)base = o;
    } else {
        const int tid = id - 8192;
        const int b = tid >> 10, rem = tid & 1023;
        const int st = rem & 31, ct = rem >> 5;
        __shared__ float tile[64][65];
        const bf16* src = vin + ((long)(b * SEQ + st * 64)) * DIMN + ct * 64;
#pragma unroll
        for (int it2 = 0; it2 < 2; it2++) {
            int idx = it2 * 256 + t;
            int r = idx >> 3, seg = idx & 7;
            bf16x8 v8 = *(const bf16x8*)(src + (long)r * DIMN + seg * 8);
#pragma unroll
            for (int qq = 0; qq < 8; qq++) tile[r][seg * 8 + qq] = (float)v8[qq];
        }
        __syncthreads();
        bf16* dst = vt + ((long)(b * DIMN + ct * 64)) * SEQ + st * 64;
#pragma unroll
        for (int it2 = 0; it2 < 2; it2++) {
            int idx = it2 * 256 + t;
            int c = idx >> 3, seg = idx & 7;
            bf16x8 o8;
#pragma unroll
            for (int qq = 0; qq < 8; qq++) o8[qq] = (bf16)tile[seg * 8 + qq][c];
            *(bf16x8*)(dst + (long)c * SEQ + seg * 8) = o8;
        }
    }
}

// -------- flash-style attention v3 + T5 setprio around MFMA clusters --------
__global__ __launch_bounds__(512, 2) void attention(
    const bf16* __restrict__ Q, const bf16* __restrict__ Kb,
    const bf16* __restrict__ Vt, bf16* __restrict__ O)
{
    __shared__ __attribute__((aligned(16))) bf16 Ksh[2][64 * 128];   // [kr][d], seg^=(kr&15)
    __shared__ __attribute__((aligned(16))) bf16 Vsh[2][128 * 64];   // [d][kr], seg^=(d&7)
    __shared__ __attribute__((aligned(16))) bf16 Psh[8][32 * 72];    // per-wave P[m][kr]
    __shared__ float Lsh[8][32];

    const int t = threadIdx.x;
    const int lane = t & 63, w = t >> 6;
    const int l15 = lane & 15, quad = lane >> 4;
    const int bh = blockIdx.x, b = bh >> 4, h = bh & 15;   // x = head: XCD-local K/V
    const int qt = blockIdx.y;
    const long qrow0 = (long)b * SEQ + qt * 256 + w * 32;
    const bf16* qbase = Q  + qrow0 * DIMN + h * HD;
    const bf16* kbase = Kb + (long)b * SEQ * DIMN + h * HD;
    const bf16* vbase = Vt + (long)bh * HD * SEQ;

    bf16x8 qf[2][4];
#pragma unroll
    for (int im = 0; im < 2; im++)
#pragma unroll
        for (int kd = 0; kd < 4; kd++)
            qf[im][kd] = *(const bf16x8*)(qbase + (long)(im * 16 + l15) * DIMN + kd * 32 + quad * 8);

    long koff[2], voff[2];
#pragma unroll
    for (int it = 0; it < 2; it++) {
        int fs = it * 512 + t;
        int kr = fs >> 4, kp = fs & 15;
        koff[it] = (long)kr * DIMN + (kp ^ (kr & 15)) * 8;
        int dr = fs >> 3, vp = fs & 7;
        voff[it] = (long)dr * SEQ + (vp ^ (dr & 7)) * 8;
    }

    f32x4 o_acc[2][8] = {};
    float Lt[2] = {0.f, 0.f};

#pragma unroll
    for (int it = 0; it < 2; it++) {
        gld_lds16(kbase + koff[it], &Ksh[0][(it * 512 + t) * 8]);
        gld_lds16(vbase + voff[it], &Vsh[0][(it * 512 + t) * 8]);
    }
    __syncthreads();

    for (int kt = 0; kt < 32; kt++) {
        const int cur = kt & 1;
        if (kt < 31) {
            const bf16* kg = kbase + (long)((kt + 1) * 64) * DIMN;
            const bf16* vg = vbase + (kt + 1) * 64;
#pragma unroll
            for (int it = 0; it < 2; it++) {
                gld_lds16(kg + koff[it], &Ksh[cur ^ 1][(it * 512 + t) * 8]);
                gld_lds16(vg + voff[it], &Vsh[cur ^ 1][(it * 512 + t) * 8]);
            }
        }
        const bf16* K0 = Ksh[cur];
        const bf16* V0 = Vsh[cur];

        // ---- S^T = K Q^T : D[kr][m] ----
        f32x4 st[4][2] = {};
        __builtin_amdgcn_s_setprio(1);
#pragma unroll
        for (int jk = 0; jk < 4; jk++)
#pragma unroll
            for (int kd = 0; kd < 4; kd++) {
                bf16x8 kf = *(const bf16x8*)(K0 + (jk * 16 + l15) * 128 + (((kd * 4 + quad) ^ l15) & 15) * 8);
                st[jk][0] = __builtin_amdgcn_mfma_f32_16x16x32_bf16(kf, qf[0][kd], st[jk][0], 0, 0, 0);
                st[jk][1] = __builtin_amdgcn_mfma_f32_16x16x32_bf16(kf, qf[1][kd], st[jk][1], 0, 0, 0);
            }
        __builtin_amdgcn_s_setprio(0);

        // ---- exp + P->LDS (b64) + per-lane partial L (reduction deferred) ----
#pragma unroll
        for (int im = 0; im < 2; im++) {
            float part = 0.f;
#pragma unroll
            for (int jk = 0; jk < 4; jk++) {
                bf16x4 pk;
#pragma unroll
                for (int r = 0; r < 4; r++) {
                    float e = __expf(st[jk][im][r]);
                    part += e;
                    pk[r] = (bf16)e;
                }
                *(bf16x4*)(Psh[w] + (im * 16 + l15) * 72 + jk * 16 + quad * 4) = pk;
            }
            Lt[im] += part;
        }
        // no barrier: Psh[w] wave-private, LDS in-order per wave

        // ---- O += P V ----
        __builtin_amdgcn_s_setprio(1);
#pragma unroll
        for (int kd2 = 0; kd2 < 2; kd2++) {
            bf16x8 pa[2];
            pa[0] = *(const bf16x8*)(Psh[w] + (l15)      * 72 + kd2 * 32 + quad * 8);
            pa[1] = *(const bf16x8*)(Psh[w] + (16 + l15) * 72 + kd2 * 32 + quad * 8);
#pragma unroll
            for (int dj = 0; dj < 8; dj++) {
                bf16x8 vfr = *(const bf16x8*)(V0 + (dj * 16 + l15) * 64 + (((kd2 * 4 + quad) ^ l15) & 7) * 8);
                o_acc[0][dj] = __builtin_amdgcn_mfma_f32_16x16x32_bf16(pa[0], vfr, o_acc[0][dj], 0, 0, 0);
                o_acc[1][dj] = __builtin_amdgcn_mfma_f32_16x16x32_bf16(pa[1], vfr, o_acc[1][dj], 0, 0, 0);
            }
        }
        __builtin_amdgcn_s_setprio(0);
        __syncthreads();   // drains this iter's prefetch (overlapped) + releases cur buffer
    }

    // deferred L reduction over quads (butterfly: all lanes hold total for m=l15)
#pragma unroll
    for (int im = 0; im < 2; im++) {
        Lt[im] += __shfl_xor(Lt[im], 16, 64);
        Lt[im] += __shfl_xor(Lt[im], 32, 64);
    }
    if (quad == 0) { Lsh[w][l15] = Lt[0]; Lsh[w][16 + l15] = Lt[1]; }
    __syncthreads();

    // normalize + write (aliases Q buffer: block (qt,bh) writes only rows/cols it alone read)
#pragma unroll
    for (int im = 0; im < 2; im++)
#pragma unroll
        for (int r = 0; r < 4; r++) {
            float inv = 1.0f / Lsh[w][im * 16 + quad * 4 + r];
            long orow = qrow0 + im * 16 + quad * 4 + r;
#pragma unroll
            for (int dj = 0; dj < 8; dj++)
                O[orow * DIMN + h * HD + dj * 16 + l15] = (bf16)(o_acc[im][dj][r] * inv);
        }
}

extern "C" void kernel_launch(void* const* d_in, const int* in_sizes, int n_in,
                              void* d_out, int out_size, void* d_ws, size_t ws_size,
                              hipStream_t stream) {
    const float* x     = (const float*)d_in[0];
    const float* freqs = (const float*)d_in[1];
    const float* wq    = (const float*)d_in[2];
    const float* bq    = (const float*)d_in[3];
    const float* wk    = (const float*)d_in[4];
    const float* bk    = (const float*)d_in[5];
    const float* wv    = (const float*)d_in[6];
    const float* bv    = (const float*)d_in[7];
    const float* wo    = (const float*)d_in[8];
    const float* bo    = (const float*)d_in[9];
    const float* gq    = (const float*)d_in[10];
    const float* gk    = (const float*)d_in[11];
    float* out = (float*)d_out;

    const size_t MAT  = (size_t)4096 * 2048 * 2;   // 16 MiB
    const size_t WMAT = (size_t)2048 * 2048 * 2;   // 8 MiB
    char* p = (char*)d_ws;
    bf16* xb  = (bf16*)p; p += MAT;
    bf16* wqb = (bf16*)p; p += WMAT;
    bf16* wkb = (bf16*)p; p += WMAT;
    bf16* wvb = (bf16*)p; p += WMAT;
    bf16* wob = (bf16*)p; p += WMAT;
    bf16* qb  = (bf16*)p; p += MAT;
    bf16* kb  = (bf16*)p; p += MAT;
    bf16* vb  = (bf16*)p; p += MAT;
    bf16* vt  = (bf16*)p; p += MAT;
    bf16* attn = qb;   // alias (safe: per-block exclusive row/col regions)

    cast_all<<<24576, 256, 0, stream>>>(x, wq, wk, wv, wo, xb, wqb, wkb, wvb, wob);

    // QKV as three exact-round dispatches (512 blocks = 2/CU each)
    gemm_bt<0><<<dim3(16, 32, 1), 256, 0, stream>>>(xb, wqb, wqb, wqb,
                                                    bq, bq, bq, qb, qb, qb);
    gemm_bt<0><<<dim3(16, 32, 1), 256, 0, stream>>>(xb, wkb, wkb, wkb,
                                                    bk, bk, bk, kb, kb, kb);
    gemm_bt<0><<<dim3(16, 32, 1), 256, 0, stream>>>(xb, wvb, wvb, wvb,
                                                    bv, bv, bv, vb, vb, vb);

    norm_prep<<<10240, 256, 0, stream>>>(qb, kb, gq, gk, freqs, vb, vt);
    attention<<<dim3(32, 8), 512, 0, stream>>>(qb, kb, vt, attn);
    gemm_bt<1><<<dim3(16, 32, 1), 256, 0, stream>>>(attn, wob, wob, wob,
                                                    bo, bo, bo, out, out, out);
}